// Round 2
// baseline (279.297 us; speedup 1.0000x reference)
//
#include <hip/hip_runtime.h>
#include <hip/hip_bf16.h>
#include <stdint.h>

// Conv4d B=1 IC=16 OC=32 K=3^4 pad=1 stride=1, D=32 -> implicit GEMM on MFMA.
// Round 5:
//  - pair-aliased B-frags: slot(p) and slot(p+3) share dd with dc+2, so
//    pbase[p+3]=pbase[p]+1088 -> load 6 contiguous c-frags, feed 8 MFMAs.
//    16 ds_read_b128 per dadb instead of 20 (-20% LDS traffic). kh=1/p=4 is
//    the zero-weight pad slot (af==0), so its aliased B content is harmless.
//  - pack_x vectorized: 4 pts/thread, float4 per ic plane, 128 B store.
//  - s_setprio(1) around the MFMA cluster (blocks at different phases/CU).
// Compute mapping + verified C/D layout identical to round 4.

typedef __bf16 bf16x8 __attribute__((ext_vector_type(8)));
typedef float f32x16 __attribute__((ext_vector_type(16)));

#define X_IC_STRIDE 1048576  // 32^4 elements per ic plane
#define W_K 1296             // 16 * 81
#define WPACK_DWORDS 23040   // 90 frags * 256 dwords (92160 B)
#define XPACK_OFF 98304      // xpack starts here in d_ws (after wpack, aligned)
#define XPACK_BYTES 33554432u // 2^20 points * 32 B ([point][g][16B])
#define ZOFF XPACK_BYTES      // 32 B zero page right after xpack
#define LDS_BYTES (13 * 256 * 16)  // 53248 B (3264 real pts + 64 pad slots)

__device__ __forceinline__ unsigned rne_bf16(float f) {
    unsigned b = __builtin_bit_cast(unsigned, f);
    return (b + 0x7FFFu + ((b >> 16) & 1u)) >> 16;
}

__device__ __forceinline__ void gload_lds16(const unsigned char* g, unsigned char* s) {
    __builtin_amdgcn_global_load_lds(
        (const __attribute__((address_space(1))) unsigned int*)g,
        (__attribute__((address_space(3))) unsigned int*)s, 16, 0, 0);
}

// Pack w[32][1296] fp32 -> wpack: 90 frags of 1024 B.
// frag fi = (g*9 + dadb)*5 + p ; within frag: lane(kh*32+oc)*16B + icpair*4B.
// slot = 2p+kh ; slot 9 = zero pad.
__global__ void pack_w_kernel(const float* __restrict__ w, unsigned* __restrict__ wpack) {
    int D = blockIdx.x * 256 + threadIdx.x;
    if (D >= WPACK_DWORDS) return;
    int t    = D & 3;          // ic pair
    int lane = (D >> 2) & 63;
    int fi   = D >> 8;
    int p    = fi % 5;
    int dadb = (fi / 5) % 9;
    int g    = fi / 45;
    int kh   = lane >> 5;
    int oc   = lane & 31;
    int slot = 2 * p + kh;
    unsigned pk = 0u;
    if (slot < 9) {
        int da = dadb / 3, db = dadb % 3;
        int dc = slot / 3, dd = slot % 3;
        int koff = da * 27 + db * 9 + dc * 3 + dd;
        int ic0  = g * 8 + 2 * t;
        unsigned lo = rne_bf16(w[oc * W_K + ic0 * 81 + koff]);
        unsigned hi = rne_bf16(w[oc * W_K + (ic0 + 1) * 81 + koff]);
        pk = lo | (hi << 16);
    }
    wpack[D] = pk;
}

// Pack x fp32 [16][2^20] -> xpack bf16 [2^20][2 groups][16 B] + 32 B zero page.
// 4 consecutive points per thread: float4 loads per ic plane (coalesced 1 KB
// per wave-inst), 128 B contiguous store per thread.
__global__ __launch_bounds__(256) void pack_x_kernel(const float* __restrict__ x,
                                                     unsigned char* __restrict__ xpack) {
    unsigned P0 = (blockIdx.x * 256 + threadIdx.x) * 4;   // grid = 1024 blocks
    float4 v[16];
#pragma unroll
    for (int ic = 0; ic < 16; ++ic)
        v[ic] = *(const float4*)(x + (size_t)ic * X_IC_STRIDE + P0);
    uint4 o[8];
#pragma unroll
    for (int pt = 0; pt < 4; ++pt) {
        unsigned u[16];
#pragma unroll
        for (int ic = 0; ic < 16; ++ic) {
            float f = (pt == 0) ? v[ic].x : (pt == 1) ? v[ic].y
                    : (pt == 2) ? v[ic].z : v[ic].w;
            u[ic] = rne_bf16(f);
        }
        o[pt * 2]     = make_uint4(u[0] | (u[1] << 16),  u[2] | (u[3] << 16),
                                   u[4] | (u[5] << 16),  u[6] | (u[7] << 16));
        o[pt * 2 + 1] = make_uint4(u[8] | (u[9] << 16),  u[10] | (u[11] << 16),
                                   u[12] | (u[13] << 16), u[14] | (u[15] << 16));
    }
#pragma unroll
    for (int j = 0; j < 8; ++j)
        *(uint4*)(xpack + (size_t)P0 * 32 + j * 16) = o[j];
    if (P0 == 0) {  // zero page for out-of-range halo points (both g offsets)
        *(uint4*)(xpack + ZOFF) = make_uint4(0u, 0u, 0u, 0u);
        *(uint4*)(xpack + ZOFF + 16) = make_uint4(0u, 0u, 0u, 0u);
    }
}

template <int XP>
__global__ __launch_bounds__(256, 3) void conv4d_mfma(
    const float* __restrict__ x,         // [16][32][32][32][32] (XP=0 path only)
    const unsigned char* __restrict__ wpack,
    const unsigned char* __restrict__ xpack,
    const float* __restrict__ bias,      // [32]
    float* __restrict__ out)             // [32][32][32][32][32]
{
    __shared__ __attribute__((aligned(16))) unsigned char lds[LDS_BYTES];

    const int tid  = threadIdx.x;
    const int lane = tid & 63;
    const int wv   = tid >> 6;     // wave 0..3
    const int kh   = lane >> 5;    // k-half -> slot select
    const int ln   = lane & 31;    // A: oc ; B: d

    // XCD-aware bijective swizzle (2048 blocks % 8 XCDs == 0).
    const int bid = blockIdx.x;
    const int blk = ((bid & 7) << 8) | (bid >> 3);
    const int c0  = (blk & 7) * 4;
    const int b0  = ((blk >> 3) & 15) * 2;
    const int a0  = (blk >> 7) * 2;
    const int ai  = wv >> 1, bi = wv & 1;

    // per-lane b-frag bases for p=0..2 (slot=2p+kh, always < 9).
    // Pair alias: pbase[p+3] == pbase[p] + 1088 (same dd, dc+2) for both kh;
    // the only exception (kh=1, p=4 -> slot 9) has af==0, any B is harmless.
    int pbase[3];
#pragma unroll
    for (int p = 0; p < 3; ++p) {
        int slot = 2 * p + kh;
        int dc = slot / 3, dd = slot % 3;
        pbase[p] = dc * 544 + (ln + dd) * 16;
    }

    // Per-thread staging source offsets, computed once (both g phases share;
    // layout [point][g][16B] makes the g adjustment a constant +16 B).
    unsigned xoff[13];
    if (XP) {
#pragma unroll
        for (int it = 0; it < 13; ++it) {
            int t   = tid + it * 256;
            int dpr = t % 34;
            int row = t / 34;
            int rc = row % 6; int r2 = row / 6;
            int rb = r2 & 3;  int ra = r2 >> 2;
            int a_in = a0 + ra - 1, b_in = b0 + rb - 1;
            int c_in = c0 + rc - 1, d_in = dpr - 1;
            bool v = ((unsigned)a_in < 32u) & ((unsigned)b_in < 32u) &
                     ((unsigned)c_in < 32u) & ((unsigned)d_in < 32u);
            unsigned P = (unsigned)(((a_in * 32 + b_in) * 32 + c_in) * 32 + d_in);
            xoff[it] = v ? P * 32u : ZOFF;
        }
    }

    f32x16 acc[4];
#pragma unroll
    for (int ci = 0; ci < 4; ++ci)
#pragma unroll
        for (int r = 0; r < 16; ++r) acc[ci][r] = 0.f;

    // ---- prime a-frag register buffer for fi=0 ----
    bf16x8 af[5];
#pragma unroll
    for (int p = 0; p < 5; ++p)
        af[p] = *(const bf16x8*)(wpack + (size_t)p * 1024 + lane * 16);

    for (int g = 0; g < 2; ++g) {
        if (g) __syncthreads();  // protect LDS before restage
        if (XP) {
            // ---- async stage: 13 global_load_lds dwordx4 per thread-slot ----
            const int gofs = g << 4;
#pragma unroll
            for (int it = 0; it < 13; ++it)
                gload_lds16(xpack + xoff[it] + gofs,
                            lds + ((it * 256 + (wv << 6)) << 4));
        } else {
            // ---- legacy stage: convert fp32->bf16 on the fly ----
            for (int t = tid; t < 96 * 34; t += 256) {
                int dpr = t % 34;
                int row = t / 34;
                int rc = row % 6; int r2 = row / 6;
                int rb = r2 & 3;  int ra = r2 >> 2;
                int a_in = a0 + ra - 1, b_in = b0 + rb - 1;
                int c_in = c0 + rc - 1, d_in = dpr - 1;
                uint4 pk = make_uint4(0u, 0u, 0u, 0u);
                if ((unsigned)a_in < 32u && (unsigned)b_in < 32u &&
                    (unsigned)c_in < 32u && (unsigned)d_in < 32u) {
                    const float* xp = x + (size_t)(g * 8) * X_IC_STRIDE +
                                      (((a_in * 32 + b_in) * 32 + c_in) * 32 + d_in);
                    unsigned u[8];
#pragma unroll
                    for (int j = 0; j < 8; ++j)
                        u[j] = rne_bf16(xp[j * X_IC_STRIDE]);
                    pk.x = u[0] | (u[1] << 16); pk.y = u[2] | (u[3] << 16);
                    pk.z = u[4] | (u[5] << 16); pk.w = u[6] | (u[7] << 16);
                }
                *(uint4*)(lds + t * 16) = pk;
            }
        }
        __syncthreads();  // drains vmcnt(0) -> staged tile visible

        for (int dadb = 0; dadb < 9; ++dadb) {
            const int fi  = g * 9 + dadb;
            const int nfi = (fi + 1 > 17) ? 17 : fi + 1;
            // prefetch next phase's a-frags (register double buffer, L2-hot)
            bf16x8 afn[5];
#pragma unroll
            for (int p = 0; p < 5; ++p)
                afn[p] = *(const bf16x8*)(wpack + ((size_t)nfi * 5 + p) * 1024 + lane * 16);

            const int da = dadb / 3, db = dadb % 3;
            const int ubase = ((ai + da) * 24 + (bi + db) * 6) * 544;

            __builtin_amdgcn_s_setprio(1);
            // paired slots (p, p+3): 6 contiguous c-frags feed 8 MFMAs
#pragma unroll
            for (int p = 0; p < 2; ++p) {
                const unsigned char* bp = lds + ubase + pbase[p];
                bf16x8 f6[6];
#pragma unroll
                for (int j = 0; j < 6; ++j)
                    f6[j] = *(const bf16x8*)(bp + j * 544);
#pragma unroll
                for (int ci = 0; ci < 4; ++ci)
                    acc[ci] = __builtin_amdgcn_mfma_f32_32x32x16_bf16(
                        af[p], f6[ci], acc[ci], 0, 0, 0);
#pragma unroll
                for (int ci = 0; ci < 4; ++ci)
                    acc[ci] = __builtin_amdgcn_mfma_f32_32x32x16_bf16(
                        af[p + 3], f6[ci + 2], acc[ci], 0, 0, 0);
            }
            // unpaired middle slot p=2
            {
                const unsigned char* bp = lds + ubase + pbase[2];
#pragma unroll
                for (int ci = 0; ci < 4; ++ci) {
                    bf16x8 bfrag = *(const bf16x8*)(bp + ci * 544);
                    acc[ci] = __builtin_amdgcn_mfma_f32_32x32x16_bf16(
                        af[2], bfrag, acc[ci], 0, 0, 0);
                }
            }
            __builtin_amdgcn_s_setprio(0);
#pragma unroll
            for (int p = 0; p < 5; ++p) af[p] = afn[p];
        }
    }

    // epilogue: D col = lane&31 = d (coalesced), row = oc = (r&3)+8*(r>>2)+4*kh
    float bv[16];
#pragma unroll
    for (int r = 0; r < 16; ++r) bv[r] = bias[(r & 3) + 8 * (r >> 2) + 4 * kh];

    const size_t sp_base = (((size_t)(a0 + ai) * 32 + (b0 + bi)) * 32 + c0);
#pragma unroll
    for (int ci = 0; ci < 4; ++ci) {
#pragma unroll
        for (int r = 0; r < 16; ++r) {
            int oc_ = (r & 3) + 8 * (r >> 2) + 4 * kh;
            out[(size_t)oc_ * X_IC_STRIDE + (sp_base + ci) * 32 + ln] = acc[ci][r] + bv[r];
        }
    }
}

extern "C" void kernel_launch(void* const* d_in, const int* in_sizes, int n_in,
                              void* d_out, int out_size, void* d_ws, size_t ws_size,
                              hipStream_t stream) {
    const float* x    = (const float*)d_in[0];
    const float* w    = (const float*)d_in[1];
    const float* bias = (const float*)d_in[2];
    float* out        = (float*)d_out;
    unsigned* wpack   = (unsigned*)d_ws;                       // 92160 B
    unsigned char* xpack = (unsigned char*)d_ws + XPACK_OFF;   // 32 MiB + 32 B

    pack_w_kernel<<<dim3((WPACK_DWORDS + 255) / 256), dim3(256), 0, stream>>>(w, wpack);
    if (ws_size >= (size_t)XPACK_OFF + XPACK_BYTES + 32) {
        pack_x_kernel<<<dim3(1024), dim3(256), 0, stream>>>(x, xpack);
        conv4d_mfma<1><<<dim3(2048), dim3(256), 0, stream>>>(
            x, (const unsigned char*)d_ws, xpack, bias, out);
    } else {
        conv4d_mfma<0><<<dim3(2048), dim3(256), 0, stream>>>(
            x, (const unsigned char*)d_ws, xpack, bias, out);
    }
}

// Round 4
// 275.525 us; speedup vs baseline: 1.0137x; 1.0137x over previous
//
#include <hip/hip_runtime.h>
#include <hip/hip_bf16.h>
#include <stdint.h>

// Conv4d B=1 IC=16 OC=32 K=3^4 pad=1 stride=1, D=32 -> implicit GEMM on MFMA.
// Round 7: robust half-tile double-buffer (recovery from round-6 NaN).
//  - TWO distinct __shared__ arrays (H0: ra 0-1, H1: ra 2-3) so alias
//    analysis separates staging writes from compute reads; no stride math.
//  - ALL sync points are __syncthreads() (vmcnt(0)+lgkmcnt(0)+barrier,
//    compiler-consistent). No counted vmcnt, no inline-asm waits.
//  - staging is full-exec only: waves issue 7/7/6/6 x global_load_lds
//    dwordx4 (1664 slots >= 1632 real; overflow slots read the zero page
//    and land in in-array pad). Wave-uniform branch, no lane divergence.
//  - overlap: g=1 restage of H0 issues before C(0,2) (reads H1 only);
//    restage of H1 issues before C(1,0) (reads H0 only). Each drain is
//    hidden under a full 60-MFMA compute step.
// Compute mapping, pair-aliased B-frags, verified C/D layout = round 5.

typedef __bf16 bf16x8 __attribute__((ext_vector_type(8)));
typedef float f32x16 __attribute__((ext_vector_type(16)));

#define X_IC_STRIDE 1048576  // 32^4 elements per ic plane
#define W_K 1296             // 16 * 81
#define WPACK_DWORDS 23040   // 90 frags * 256 dwords (92160 B)
#define XPACK_OFF 98304      // xpack starts here in d_ws (after wpack)
#define XPACK_BYTES 33554432u // 2^20 points * 32 B ([point][g][16B])
#define ZOFF XPACK_BYTES      // 32 B zero page right after xpack
#define H_SLOTS 1632          // 48 rows * 34 pts per half
#define H_BYTES 26624         // 1664 slots * 16 B (32-slot pad for overflow)
#define LEGACY_LDS 52224      // legacy fallback kernel

__device__ __forceinline__ unsigned rne_bf16(float f) {
    unsigned b = __builtin_bit_cast(unsigned, f);
    return (b + 0x7FFFu + ((b >> 16) & 1u)) >> 16;
}

__device__ __forceinline__ void gload_lds16(const unsigned char* g, unsigned char* s) {
    __builtin_amdgcn_global_load_lds(
        (const __attribute__((address_space(1))) unsigned int*)g,
        (__attribute__((address_space(3))) unsigned int*)s, 16, 0, 0);
}

__device__ __forceinline__ void fence_sched() { __builtin_amdgcn_sched_barrier(0); }

// Pack w[32][1296] fp32 -> wpack: 90 frags of 1024 B.
// frag fi = (g*9 + dadb)*5 + p ; within frag: lane(kh*32+oc)*16B + icpair*4B.
// slot = 2p+kh ; slot 9 = zero pad.
__global__ void pack_w_kernel(const float* __restrict__ w, unsigned* __restrict__ wpack) {
    int D = blockIdx.x * 256 + threadIdx.x;
    if (D >= WPACK_DWORDS) return;
    int t    = D & 3;          // ic pair
    int lane = (D >> 2) & 63;
    int fi   = D >> 8;
    int p    = fi % 5;
    int dadb = (fi / 5) % 9;
    int g    = fi / 45;
    int kh   = lane >> 5;
    int oc   = lane & 31;
    int slot = 2 * p + kh;
    unsigned pk = 0u;
    if (slot < 9) {
        int da = dadb / 3, db = dadb % 3;
        int dc = slot / 3, dd = slot % 3;
        int koff = da * 27 + db * 9 + dc * 3 + dd;
        int ic0  = g * 8 + 2 * t;
        unsigned lo = rne_bf16(w[oc * W_K + ic0 * 81 + koff]);
        unsigned hi = rne_bf16(w[oc * W_K + (ic0 + 1) * 81 + koff]);
        pk = lo | (hi << 16);
    }
    wpack[D] = pk;
}

// Pack x fp32 [16][2^20] -> xpack bf16 [2^20][2 groups][16 B] + zero page.
__global__ __launch_bounds__(256) void pack_x_kernel(const float* __restrict__ x,
                                                     unsigned char* __restrict__ xpack) {
    unsigned P0 = (blockIdx.x * 256 + threadIdx.x) * 4;   // grid = 1024 blocks
    float4 v[16];
#pragma unroll
    for (int ic = 0; ic < 16; ++ic)
        v[ic] = *(const float4*)(x + (size_t)ic * X_IC_STRIDE + P0);
    uint4 o[8];
#pragma unroll
    for (int pt = 0; pt < 4; ++pt) {
        unsigned u[16];
#pragma unroll
        for (int ic = 0; ic < 16; ++ic) {
            float f = (pt == 0) ? v[ic].x : (pt == 1) ? v[ic].y
                    : (pt == 2) ? v[ic].z : v[ic].w;
            u[ic] = rne_bf16(f);
        }
        o[pt * 2]     = make_uint4(u[0] | (u[1] << 16),  u[2] | (u[3] << 16),
                                   u[4] | (u[5] << 16),  u[6] | (u[7] << 16));
        o[pt * 2 + 1] = make_uint4(u[8] | (u[9] << 16),  u[10] | (u[11] << 16),
                                   u[12] | (u[13] << 16), u[14] | (u[15] << 16));
    }
#pragma unroll
    for (int j = 0; j < 8; ++j)
        *(uint4*)(xpack + (size_t)P0 * 32 + j * 16) = o[j];
    if (P0 == 0) {
        *(uint4*)(xpack + ZOFF) = make_uint4(0u, 0u, 0u, 0u);
        *(uint4*)(xpack + ZOFF + 16) = make_uint4(0u, 0u, 0u, 0u);
    }
}

__global__ __launch_bounds__(256, 3) void conv4d_pipe(
    const unsigned char* __restrict__ wpack,
    const unsigned char* __restrict__ xpack,
    const float* __restrict__ bias,      // [32]
    float* __restrict__ out)             // [32][32][32][32][32]
{
    // Two separate halves: compiler can prove staging(H0) !alias reads(H1).
    __shared__ __attribute__((aligned(16))) unsigned char ldsH0[H_BYTES];
    __shared__ __attribute__((aligned(16))) unsigned char ldsH1[H_BYTES];

    const int tid  = threadIdx.x;
    const int lane = tid & 63;
    const int wv   = tid >> 6;     // wave 0..3
    const int kh   = lane >> 5;    // k-half -> slot select
    const int ln   = lane & 31;    // A: oc ; B: d

    // XCD-aware bijective swizzle (2048 blocks % 8 XCDs == 0).
    const int bid = blockIdx.x;
    const int blk = ((bid & 7) << 8) | (bid >> 3);
    const int c0  = (blk & 7) * 4;
    const int b0  = ((blk >> 3) & 15) * 2;
    const int a0  = (blk >> 7) * 2;
    const int ai  = wv >> 1, bi = wv & 1;

    // per-lane b-frag bases for p=0..2 (pair alias: pbase[p+3]=pbase[p]+1088;
    // the only unpaired case kh=1,p=4 is the zero-weight pad slot, af==0).
    int pbase[3];
#pragma unroll
    for (int p = 0; p < 3; ++p) {
        int slot = 2 * p + kh;
        int dc = slot / 3, dd = slot % 3;
        pbase[p] = dc * 544 + (ln + dd) * 16;
    }

    // Staging split: waves stage 7/7/6/6 full 64-lane loads per half.
    const int nld   = (wv < 2) ? 7 : 6;
    const int sbase = (wv < 2) ? wv * 448 : 896 + (wv - 2) * 384;

    // Per-thread staging source offsets (both g phases share; layout
    // [point][g][16B] makes the g adjustment a constant +16 B).
    unsigned xoffH[2][7];
#pragma unroll
    for (int h = 0; h < 2; ++h)
#pragma unroll
        for (int i = 0; i < 7; ++i) {
            int s   = sbase + i * 64 + lane;
            int row = h * 48 + s / 34;       // global row (ra*4+rb)*6+rc
            int dpr = s % 34;
            int rc = row % 6; int r2 = row / 6;
            int rb = r2 & 3;  int ra = r2 >> 2;
            int a_in = a0 + ra - 1, b_in = b0 + rb - 1;
            int c_in = c0 + rc - 1, d_in = dpr - 1;
            bool v = (s < H_SLOTS) &
                     ((unsigned)a_in < 32u) & ((unsigned)b_in < 32u) &
                     ((unsigned)c_in < 32u) & ((unsigned)d_in < 32u);
            unsigned P = (unsigned)(((a_in * 32 + b_in) * 32 + c_in) * 32 + d_in);
            xoffH[h][i] = v ? P * 32u : ZOFF;
        }

    f32x16 acc[4];
#pragma unroll
    for (int ci = 0; ci < 4; ++ci)
#pragma unroll
        for (int r = 0; r < 16; ++r) acc[ci][r] = 0.f;

    bf16x8 af[5];

    // stage one half for ic-group g: nld full-exec global_load_lds dwordx4
    auto stage_half = [&](unsigned char* dstArr, int h, int g) {
        const unsigned gofs = (unsigned)(g << 4);
        unsigned char* base = dstArr + (sbase << 4);
#pragma unroll
        for (int i = 0; i < 7; ++i) {
            if (i < 6 || wv < 2) {   // wave-uniform; no lane divergence
                if (i < nld)
                    gload_lds16(xpack + xoffH[h][i] + gofs, base + ((i * 64) << 4));
            }
        }
    };

    // compute step (g, da): 3 db iterations, 60 MFMA / 48 ds_read per wave
    auto cstep = [&](int g, int da) {
        const int ca = ai + da;                       // 0..3, wave-uniform
        const unsigned char* hb = ((ca & 2) ? ldsH1 : ldsH0) + (ca & 1) * 13056;
#pragma unroll
        for (int db = 0; db < 3; ++db) {
            const int fi  = g * 9 + da * 3 + db;
            const int nfi = (fi + 1 > 17) ? 17 : fi + 1;
            bf16x8 afn[5];
#pragma unroll
            for (int p = 0; p < 5; ++p)
                afn[p] = *(const bf16x8*)(wpack + ((size_t)nfi * 5 + p) * 1024 + lane * 16);

            const unsigned char* rbase = hb + (bi + db) * 3264;   // (bi+db)*6*544
            __builtin_amdgcn_s_setprio(1);
#pragma unroll
            for (int p = 0; p < 2; ++p) {
                const unsigned char* bp = rbase + pbase[p];
                bf16x8 f6[6];
#pragma unroll
                for (int j = 0; j < 6; ++j)
                    f6[j] = *(const bf16x8*)(bp + j * 544);
#pragma unroll
                for (int ci = 0; ci < 4; ++ci)
                    acc[ci] = __builtin_amdgcn_mfma_f32_32x32x16_bf16(
                        af[p], f6[ci], acc[ci], 0, 0, 0);
#pragma unroll
                for (int ci = 0; ci < 4; ++ci)
                    acc[ci] = __builtin_amdgcn_mfma_f32_32x32x16_bf16(
                        af[p + 3], f6[ci + 2], acc[ci], 0, 0, 0);
            }
            {
                const unsigned char* bp = rbase + pbase[2];
#pragma unroll
                for (int ci = 0; ci < 4; ++ci) {
                    bf16x8 bfrag = *(const bf16x8*)(bp + ci * 544);
                    acc[ci] = __builtin_amdgcn_mfma_f32_32x32x16_bf16(
                        af[2], bfrag, acc[ci], 0, 0, 0);
                }
            }
            __builtin_amdgcn_s_setprio(0);
#pragma unroll
            for (int p = 0; p < 5; ++p) af[p] = afn[p];
        }
    };

    // ---------------- pipelined schedule (all waits = __syncthreads) -------
    stage_half(ldsH0, 0, 0);
    stage_half(ldsH1, 1, 0);
#pragma unroll
    for (int p = 0; p < 5; ++p)
        af[p] = *(const bf16x8*)(wpack + (size_t)p * 1024 + lane * 16);
    __syncthreads();            // A: drains staging; tiles ready

    cstep(0, 0);                // reads H0
    cstep(0, 1);                // reads H0+H1
    __syncthreads();            // B: all waves done reading H0(g0); ~nothing in flight

    stage_half(ldsH0, 0, 1);    // S2 issued early, drains under next cstep
    fence_sched();
    cstep(0, 2);                // reads H1 only
    __syncthreads();            // C: drains S2 -> H0' ready; H1(g0) fully read

    stage_half(ldsH1, 1, 1);    // S3 issued early, drains under next cstep
    fence_sched();
    cstep(1, 0);                // reads H0' only
    __syncthreads();            // D: drains S3 -> H1' ready

    cstep(1, 1);                // reads H0'+H1'
    cstep(1, 2);                // reads H1'

    // epilogue: D col = lane&31 = d (coalesced), row oc = (r&3)+8*(r>>2)+4*kh
    float bv[16];
#pragma unroll
    for (int r = 0; r < 16; ++r) bv[r] = bias[(r & 3) + 8 * (r >> 2) + 4 * kh];

    const size_t sp_base = (((size_t)(a0 + ai) * 32 + (b0 + bi)) * 32 + c0);
#pragma unroll
    for (int ci = 0; ci < 4; ++ci) {
#pragma unroll
        for (int r = 0; r < 16; ++r) {
            int oc_ = (r & 3) + 8 * (r >> 2) + 4 * kh;
            out[(size_t)oc_ * X_IC_STRIDE + (sp_base + ci) * 32 + ln] = acc[ci][r] + bv[r];
        }
    }
}

// Legacy fallback (ws too small for xpack): round-5 structure, on-the-fly cvt.
__global__ __launch_bounds__(256, 3) void conv4d_legacy(
    const float* __restrict__ x,
    const unsigned char* __restrict__ wpack,
    const float* __restrict__ bias,
    float* __restrict__ out)
{
    __shared__ __attribute__((aligned(16))) unsigned char lds[LEGACY_LDS];

    const int tid  = threadIdx.x;
    const int lane = tid & 63;
    const int wv   = tid >> 6;
    const int kh   = lane >> 5;
    const int ln   = lane & 31;

    const int bid = blockIdx.x;
    const int blk = ((bid & 7) << 8) | (bid >> 3);
    const int c0  = (blk & 7) * 4;
    const int b0  = ((blk >> 3) & 15) * 2;
    const int a0  = (blk >> 7) * 2;
    const int ai  = wv >> 1, bi = wv & 1;

    int pbase[3];
#pragma unroll
    for (int p = 0; p < 3; ++p) {
        int slot = 2 * p + kh;
        int dc = slot / 3, dd = slot % 3;
        pbase[p] = dc * 544 + (ln + dd) * 16;
    }

    f32x16 acc[4];
#pragma unroll
    for (int ci = 0; ci < 4; ++ci)
#pragma unroll
        for (int r = 0; r < 16; ++r) acc[ci][r] = 0.f;

    bf16x8 af[5];
#pragma unroll
    for (int p = 0; p < 5; ++p)
        af[p] = *(const bf16x8*)(wpack + (size_t)p * 1024 + lane * 16);

    for (int g = 0; g < 2; ++g) {
        if (g) __syncthreads();
        for (int t = tid; t < 96 * 34; t += 256) {
            int dpr = t % 34;
            int row = t / 34;
            int rc = row % 6; int r2 = row / 6;
            int rb = r2 & 3;  int ra = r2 >> 2;
            int a_in = a0 + ra - 1, b_in = b0 + rb - 1;
            int c_in = c0 + rc - 1, d_in = dpr - 1;
            uint4 pk = make_uint4(0u, 0u, 0u, 0u);
            if ((unsigned)a_in < 32u && (unsigned)b_in < 32u &&
                (unsigned)c_in < 32u && (unsigned)d_in < 32u) {
                const float* xp = x + (size_t)(g * 8) * X_IC_STRIDE +
                                  (((a_in * 32 + b_in) * 32 + c_in) * 32 + d_in);
                unsigned u[8];
#pragma unroll
                for (int j = 0; j < 8; ++j)
                    u[j] = rne_bf16(xp[j * X_IC_STRIDE]);
                pk.x = u[0] | (u[1] << 16); pk.y = u[2] | (u[3] << 16);
                pk.z = u[4] | (u[5] << 16); pk.w = u[6] | (u[7] << 16);
            }
            *(uint4*)(lds + t * 16) = pk;
        }
        __syncthreads();

        for (int dadb = 0; dadb < 9; ++dadb) {
            const int fi  = g * 9 + dadb;
            const int nfi = (fi + 1 > 17) ? 17 : fi + 1;
            bf16x8 afn[5];
#pragma unroll
            for (int p = 0; p < 5; ++p)
                afn[p] = *(const bf16x8*)(wpack + ((size_t)nfi * 5 + p) * 1024 + lane * 16);

            const int da = dadb / 3, db = dadb % 3;
            const int ubase = ((ai + da) * 24 + (bi + db) * 6) * 544;
#pragma unroll
            for (int p = 0; p < 2; ++p) {
                const unsigned char* bp = lds + ubase + pbase[p];
                bf16x8 f6[6];
#pragma unroll
                for (int j = 0; j < 6; ++j)
                    f6[j] = *(const bf16x8*)(bp + j * 544);
#pragma unroll
                for (int ci = 0; ci < 4; ++ci)
                    acc[ci] = __builtin_amdgcn_mfma_f32_32x32x16_bf16(
                        af[p], f6[ci], acc[ci], 0, 0, 0);
#pragma unroll
                for (int ci = 0; ci < 4; ++ci)
                    acc[ci] = __builtin_amdgcn_mfma_f32_32x32x16_bf16(
                        af[p + 3], f6[ci + 2], acc[ci], 0, 0, 0);
            }
            {
                const unsigned char* bp = lds + ubase + pbase[2];
#pragma unroll
                for (int ci = 0; ci < 4; ++ci) {
                    bf16x8 bfrag = *(const bf16x8*)(bp + ci * 544);
                    acc[ci] = __builtin_amdgcn_mfma_f32_32x32x16_bf16(
                        af[2], bfrag, acc[ci], 0, 0, 0);
                }
            }
#pragma unroll
            for (int p = 0; p < 5; ++p) af[p] = afn[p];
        }
    }

    float bv[16];
#pragma unroll
    for (int r = 0; r < 16; ++r) bv[r] = bias[(r & 3) + 8 * (r >> 2) + 4 * kh];

    const size_t sp_base = (((size_t)(a0 + ai) * 32 + (b0 + bi)) * 32 + c0);
#pragma unroll
    for (int ci = 0; ci < 4; ++ci) {
#pragma unroll
        for (int r = 0; r < 16; ++r) {
            int oc_ = (r & 3) + 8 * (r >> 2) + 4 * kh;
            out[(size_t)oc_ * X_IC_STRIDE + (sp_base + ci) * 32 + ln] = acc[ci][r] + bv[r];
        }
    }
}

extern "C" void kernel_launch(void* const* d_in, const int* in_sizes, int n_in,
                              void* d_out, int out_size, void* d_ws, size_t ws_size,
                              hipStream_t stream) {
    const float* x    = (const float*)d_in[0];
    const float* w    = (const float*)d_in[1];
    const float* bias = (const float*)d_in[2];
    float* out        = (float*)d_out;
    unsigned* wpack   = (unsigned*)d_ws;                       // 92160 B
    unsigned char* xpack = (unsigned char*)d_ws + XPACK_OFF;   // 32 MiB + 32 B

    pack_w_kernel<<<dim3((WPACK_DWORDS + 255) / 256), dim3(256), 0, stream>>>(w, wpack);
    if (ws_size >= (size_t)XPACK_OFF + XPACK_BYTES + 32) {
        pack_x_kernel<<<dim3(1024), dim3(256), 0, stream>>>(x, xpack);
        conv4d_pipe<<<dim3(2048), dim3(256), 0, stream>>>(
            (const unsigned char*)d_ws, xpack, bias, out);
    } else {
        conv4d_legacy<<<dim3(2048), dim3(256), 0, stream>>>(
            x, (const unsigned char*)d_ws, bias, out);
    }
}

// Round 5
// 259.194 us; speedup vs baseline: 1.0776x; 1.0630x over previous
//
#include <hip/hip_runtime.h>
#include <hip/hip_bf16.h>
#include <stdint.h>

// Conv4d B=1 IC=16 OC=32 K=3^4 pad=1 stride=1, D=32 -> implicit GEMM on MFMA.
// Round 8: pack-path overhaul (conv kernel byte-identical to verified round 7).
//  - pack_x v3: 2 pts/thread via float2 plane loads (512 B/wave-inst), ~60
//    live VGPRs -> 8 waves/SIMD, grid 2048, 64 B contiguous store/thread.
//    (Round-2 float4 version held 96 VGPRs live -> spill risk + low TLP;
//    measured ~59 us. Floor is 96 MB / 6.3 TB/s = 15 us.)
//  - pack_w fused into the same kernel (first 90 blocks dual-duty): one
//    fewer serialized launch in the graph.
// Conv: half-tile double-buffer, all waits __syncthreads, pair-aliased
// B-frags, verified C/D layout (round 7, passed, 90.5 us).

typedef __bf16 bf16x8 __attribute__((ext_vector_type(8)));
typedef float f32x16 __attribute__((ext_vector_type(16)));

#define X_IC_STRIDE 1048576  // 32^4 elements per ic plane
#define W_K 1296             // 16 * 81
#define WPACK_DWORDS 23040   // 90 frags * 256 dwords (92160 B)
#define XPACK_OFF 98304      // xpack starts here in d_ws (after wpack)
#define XPACK_BYTES 33554432u // 2^20 points * 32 B ([point][g][16B])
#define ZOFF XPACK_BYTES      // 32 B zero page right after xpack
#define H_SLOTS 1632          // 48 rows * 34 pts per half
#define H_BYTES 26624         // 1664 slots * 16 B (32-slot pad for overflow)
#define LEGACY_LDS 52224      // legacy fallback kernel

__device__ __forceinline__ unsigned rne_bf16(float f) {
    unsigned b = __builtin_bit_cast(unsigned, f);
    return (b + 0x7FFFu + ((b >> 16) & 1u)) >> 16;
}

__device__ __forceinline__ void gload_lds16(const unsigned char* g, unsigned char* s) {
    __builtin_amdgcn_global_load_lds(
        (const __attribute__((address_space(1))) unsigned int*)g,
        (__attribute__((address_space(3))) unsigned int*)s, 16, 0, 0);
}

__device__ __forceinline__ void fence_sched() { __builtin_amdgcn_sched_barrier(0); }

// w-pack body (shared by fused kernel and legacy pack_w).
// frag fi = (g*9 + dadb)*5 + p ; within frag: lane(kh*32+oc)*16B + icpair*4B.
// slot = 2p+kh ; slot 9 = zero pad.
__device__ __forceinline__ void pack_w_body(int D, const float* __restrict__ w,
                                            unsigned* __restrict__ wpack) {
    if (D >= WPACK_DWORDS) return;
    int t    = D & 3;          // ic pair
    int lane = (D >> 2) & 63;
    int fi   = D >> 8;
    int p    = fi % 5;
    int dadb = (fi / 5) % 9;
    int g    = fi / 45;
    int kh   = lane >> 5;
    int oc   = lane & 31;
    int slot = 2 * p + kh;
    unsigned pk = 0u;
    if (slot < 9) {
        int da = dadb / 3, db = dadb % 3;
        int dc = slot / 3, dd = slot % 3;
        int koff = da * 27 + db * 9 + dc * 3 + dd;
        int ic0  = g * 8 + 2 * t;
        unsigned lo = rne_bf16(w[oc * W_K + ic0 * 81 + koff]);
        unsigned hi = rne_bf16(w[oc * W_K + (ic0 + 1) * 81 + koff]);
        pk = lo | (hi << 16);
    }
    wpack[D] = pk;
}

__global__ void pack_w_kernel(const float* __restrict__ w, unsigned* __restrict__ wpack) {
    pack_w_body(blockIdx.x * 256 + threadIdx.x, w, wpack);
}

// Fused pack: x fp32 [16][2^20] -> xpack bf16 [2^20][2 g][16 B] (+zero page),
// and (first 90 blocks) w -> wpack. 2 points per thread, float2 plane loads.
__global__ __launch_bounds__(256) void pack_xw_kernel(const float* __restrict__ x,
                                                      const float* __restrict__ w,
                                                      unsigned char* __restrict__ xpack,
                                                      unsigned* __restrict__ wpack) {
    const int bid = blockIdx.x;          // grid = 2048
    const int tid = threadIdx.x;
    if (bid < (WPACK_DWORDS + 255) / 256)
        pack_w_body(bid * 256 + tid, w, wpack);

    const unsigned P0 = (unsigned)(bid * 256 + tid) * 2u;   // 2 pts/thread
    float2 v[16];
#pragma unroll
    for (int ic = 0; ic < 16; ++ic)
        v[ic] = *(const float2*)(x + (size_t)ic * X_IC_STRIDE + P0);

    uint4 o[4];
#pragma unroll
    for (int pt = 0; pt < 2; ++pt) {
        unsigned u[16];
#pragma unroll
        for (int ic = 0; ic < 16; ++ic)
            u[ic] = rne_bf16(pt ? v[ic].y : v[ic].x);
        o[pt * 2]     = make_uint4(u[0] | (u[1] << 16),  u[2] | (u[3] << 16),
                                   u[4] | (u[5] << 16),  u[6] | (u[7] << 16));
        o[pt * 2 + 1] = make_uint4(u[8] | (u[9] << 16),  u[10] | (u[11] << 16),
                                   u[12] | (u[13] << 16), u[14] | (u[15] << 16));
    }
#pragma unroll
    for (int j = 0; j < 4; ++j)
        *(uint4*)(xpack + (size_t)P0 * 32 + j * 16) = o[j];

    if (P0 == 0) {   // zero page for out-of-range halo points
        *(uint4*)(xpack + ZOFF) = make_uint4(0u, 0u, 0u, 0u);
        *(uint4*)(xpack + ZOFF + 16) = make_uint4(0u, 0u, 0u, 0u);
    }
}

__global__ __launch_bounds__(256, 3) void conv4d_pipe(
    const unsigned char* __restrict__ wpack,
    const unsigned char* __restrict__ xpack,
    const float* __restrict__ bias,      // [32]
    float* __restrict__ out)             // [32][32][32][32][32]
{
    // Two separate halves: compiler can prove staging(H0) !alias reads(H1).
    __shared__ __attribute__((aligned(16))) unsigned char ldsH0[H_BYTES];
    __shared__ __attribute__((aligned(16))) unsigned char ldsH1[H_BYTES];

    const int tid  = threadIdx.x;
    const int lane = tid & 63;
    const int wv   = tid >> 6;     // wave 0..3
    const int kh   = lane >> 5;    // k-half -> slot select
    const int ln   = lane & 31;    // A: oc ; B: d

    // XCD-aware bijective swizzle (2048 blocks % 8 XCDs == 0).
    const int bid = blockIdx.x;
    const int blk = ((bid & 7) << 8) | (bid >> 3);
    const int c0  = (blk & 7) * 4;
    const int b0  = ((blk >> 3) & 15) * 2;
    const int a0  = (blk >> 7) * 2;
    const int ai  = wv >> 1, bi = wv & 1;

    // per-lane b-frag bases for p=0..2 (pair alias: pbase[p+3]=pbase[p]+1088;
    // the only unpaired case kh=1,p=4 is the zero-weight pad slot, af==0).
    int pbase[3];
#pragma unroll
    for (int p = 0; p < 3; ++p) {
        int slot = 2 * p + kh;
        int dc = slot / 3, dd = slot % 3;
        pbase[p] = dc * 544 + (ln + dd) * 16;
    }

    // Staging split: waves stage 7/7/6/6 full 64-lane loads per half.
    const int nld   = (wv < 2) ? 7 : 6;
    const int sbase = (wv < 2) ? wv * 448 : 896 + (wv - 2) * 384;

    // Per-thread staging source offsets (both g phases share; layout
    // [point][g][16B] makes the g adjustment a constant +16 B).
    unsigned xoffH[2][7];
#pragma unroll
    for (int h = 0; h < 2; ++h)
#pragma unroll
        for (int i = 0; i < 7; ++i) {
            int s   = sbase + i * 64 + lane;
            int row = h * 48 + s / 34;       // global row (ra*4+rb)*6+rc
            int dpr = s % 34;
            int rc = row % 6; int r2 = row / 6;
            int rb = r2 & 3;  int ra = r2 >> 2;
            int a_in = a0 + ra - 1, b_in = b0 + rb - 1;
            int c_in = c0 + rc - 1, d_in = dpr - 1;
            bool v = (s < H_SLOTS) &
                     ((unsigned)a_in < 32u) & ((unsigned)b_in < 32u) &
                     ((unsigned)c_in < 32u) & ((unsigned)d_in < 32u);
            unsigned P = (unsigned)(((a_in * 32 + b_in) * 32 + c_in) * 32 + d_in);
            xoffH[h][i] = v ? P * 32u : ZOFF;
        }

    f32x16 acc[4];
#pragma unroll
    for (int ci = 0; ci < 4; ++ci)
#pragma unroll
        for (int r = 0; r < 16; ++r) acc[ci][r] = 0.f;

    bf16x8 af[5];

    // stage one half for ic-group g: nld full-exec global_load_lds dwordx4
    auto stage_half = [&](unsigned char* dstArr, int h, int g) {
        const unsigned gofs = (unsigned)(g << 4);
        unsigned char* base = dstArr + (sbase << 4);
#pragma unroll
        for (int i = 0; i < 7; ++i) {
            if (i < 6 || wv < 2) {   // wave-uniform; no lane divergence
                if (i < nld)
                    gload_lds16(xpack + xoffH[h][i] + gofs, base + ((i * 64) << 4));
            }
        }
    };

    // compute step (g, da): 3 db iterations, 60 MFMA / 48 ds_read per wave
    auto cstep = [&](int g, int da) {
        const int ca = ai + da;                       // 0..3, wave-uniform
        const unsigned char* hb = ((ca & 2) ? ldsH1 : ldsH0) + (ca & 1) * 13056;
#pragma unroll
        for (int db = 0; db < 3; ++db) {
            const int fi  = g * 9 + da * 3 + db;
            const int nfi = (fi + 1 > 17) ? 17 : fi + 1;
            bf16x8 afn[5];
#pragma unroll
            for (int p = 0; p < 5; ++p)
                afn[p] = *(const bf16x8*)(wpack + ((size_t)nfi * 5 + p) * 1024 + lane * 16);

            const unsigned char* rbase = hb + (bi + db) * 3264;   // (bi+db)*6*544
            __builtin_amdgcn_s_setprio(1);
#pragma unroll
            for (int p = 0; p < 2; ++p) {
                const unsigned char* bp = rbase + pbase[p];
                bf16x8 f6[6];
#pragma unroll
                for (int j = 0; j < 6; ++j)
                    f6[j] = *(const bf16x8*)(bp + j * 544);
#pragma unroll
                for (int ci = 0; ci < 4; ++ci)
                    acc[ci] = __builtin_amdgcn_mfma_f32_32x32x16_bf16(
                        af[p], f6[ci], acc[ci], 0, 0, 0);
#pragma unroll
                for (int ci = 0; ci < 4; ++ci)
                    acc[ci] = __builtin_amdgcn_mfma_f32_32x32x16_bf16(
                        af[p + 3], f6[ci + 2], acc[ci], 0, 0, 0);
            }
            {
                const unsigned char* bp = rbase + pbase[2];
#pragma unroll
                for (int ci = 0; ci < 4; ++ci) {
                    bf16x8 bfrag = *(const bf16x8*)(bp + ci * 544);
                    acc[ci] = __builtin_amdgcn_mfma_f32_32x32x16_bf16(
                        af[2], bfrag, acc[ci], 0, 0, 0);
                }
            }
            __builtin_amdgcn_s_setprio(0);
#pragma unroll
            for (int p = 0; p < 5; ++p) af[p] = afn[p];
        }
    };

    // ---------------- pipelined schedule (all waits = __syncthreads) -------
    stage_half(ldsH0, 0, 0);
    stage_half(ldsH1, 1, 0);
#pragma unroll
    for (int p = 0; p < 5; ++p)
        af[p] = *(const bf16x8*)(wpack + (size_t)p * 1024 + lane * 16);
    __syncthreads();            // A: drains staging; tiles ready

    cstep(0, 0);                // reads H0
    cstep(0, 1);                // reads H0+H1
    __syncthreads();            // B: all waves done reading H0(g0)

    stage_half(ldsH0, 0, 1);    // S2 issued early, drains under next cstep
    fence_sched();
    cstep(0, 2);                // reads H1 only
    __syncthreads();            // C: drains S2 -> H0' ready; H1(g0) fully read

    stage_half(ldsH1, 1, 1);    // S3 issued early, drains under next cstep
    fence_sched();
    cstep(1, 0);                // reads H0' only
    __syncthreads();            // D: drains S3 -> H1' ready

    cstep(1, 1);                // reads H0'+H1'
    cstep(1, 2);                // reads H1'

    // epilogue: D col = lane&31 = d (coalesced), row oc = (r&3)+8*(r>>2)+4*kh
    float bv[16];
#pragma unroll
    for (int r = 0; r < 16; ++r) bv[r] = bias[(r & 3) + 8 * (r >> 2) + 4 * kh];

    const size_t sp_base = (((size_t)(a0 + ai) * 32 + (b0 + bi)) * 32 + c0);
#pragma unroll
    for (int ci = 0; ci < 4; ++ci) {
#pragma unroll
        for (int r = 0; r < 16; ++r) {
            int oc_ = (r & 3) + 8 * (r >> 2) + 4 * kh;
            out[(size_t)oc_ * X_IC_STRIDE + (sp_base + ci) * 32 + ln] = acc[ci][r] + bv[r];
        }
    }
}

// Legacy fallback (ws too small for xpack): on-the-fly cvt staging.
__global__ __launch_bounds__(256, 3) void conv4d_legacy(
    const float* __restrict__ x,
    const unsigned char* __restrict__ wpack,
    const float* __restrict__ bias,
    float* __restrict__ out)
{
    __shared__ __attribute__((aligned(16))) unsigned char lds[LEGACY_LDS];

    const int tid  = threadIdx.x;
    const int lane = tid & 63;
    const int wv   = tid >> 6;
    const int kh   = lane >> 5;
    const int ln   = lane & 31;

    const int bid = blockIdx.x;
    const int blk = ((bid & 7) << 8) | (bid >> 3);
    const int c0  = (blk & 7) * 4;
    const int b0  = ((blk >> 3) & 15) * 2;
    const int a0  = (blk >> 7) * 2;
    const int ai  = wv >> 1, bi = wv & 1;

    int pbase[3];
#pragma unroll
    for (int p = 0; p < 3; ++p) {
        int slot = 2 * p + kh;
        int dc = slot / 3, dd = slot % 3;
        pbase[p] = dc * 544 + (ln + dd) * 16;
    }

    f32x16 acc[4];
#pragma unroll
    for (int ci = 0; ci < 4; ++ci)
#pragma unroll
        for (int r = 0; r < 16; ++r) acc[ci][r] = 0.f;

    bf16x8 af[5];
#pragma unroll
    for (int p = 0; p < 5; ++p)
        af[p] = *(const bf16x8*)(wpack + (size_t)p * 1024 + lane * 16);

    for (int g = 0; g < 2; ++g) {
        if (g) __syncthreads();
        for (int t = tid; t < 96 * 34; t += 256) {
            int dpr = t % 34;
            int row = t / 34;
            int rc = row % 6; int r2 = row / 6;
            int rb = r2 & 3;  int ra = r2 >> 2;
            int a_in = a0 + ra - 1, b_in = b0 + rb - 1;
            int c_in = c0 + rc - 1, d_in = dpr - 1;
            uint4 pk = make_uint4(0u, 0u, 0u, 0u);
            if ((unsigned)a_in < 32u && (unsigned)b_in < 32u &&
                (unsigned)c_in < 32u && (unsigned)d_in < 32u) {
                const float* xp = x + (size_t)(g * 8) * X_IC_STRIDE +
                                  (((a_in * 32 + b_in) * 32 + c_in) * 32 + d_in);
                unsigned u[8];
#pragma unroll
                for (int j = 0; j < 8; ++j)
                    u[j] = rne_bf16(xp[j * X_IC_STRIDE]);
                pk.x = u[0] | (u[1] << 16); pk.y = u[2] | (u[3] << 16);
                pk.z = u[4] | (u[5] << 16); pk.w = u[6] | (u[7] << 16);
            }
            *(uint4*)(lds + t * 16) = pk;
        }
        __syncthreads();

        for (int dadb = 0; dadb < 9; ++dadb) {
            const int fi  = g * 9 + dadb;
            const int nfi = (fi + 1 > 17) ? 17 : fi + 1;
            bf16x8 afn[5];
#pragma unroll
            for (int p = 0; p < 5; ++p)
                afn[p] = *(const bf16x8*)(wpack + ((size_t)nfi * 5 + p) * 1024 + lane * 16);

            const int da = dadb / 3, db = dadb % 3;
            const int ubase = ((ai + da) * 24 + (bi + db) * 6) * 544;
#pragma unroll
            for (int p = 0; p < 2; ++p) {
                const unsigned char* bp = lds + ubase + pbase[p];
                bf16x8 f6[6];
#pragma unroll
                for (int j = 0; j < 6; ++j)
                    f6[j] = *(const bf16x8*)(bp + j * 544);
#pragma unroll
                for (int ci = 0; ci < 4; ++ci)
                    acc[ci] = __builtin_amdgcn_mfma_f32_32x32x16_bf16(
                        af[p], f6[ci], acc[ci], 0, 0, 0);
#pragma unroll
                for (int ci = 0; ci < 4; ++ci)
                    acc[ci] = __builtin_amdgcn_mfma_f32_32x32x16_bf16(
                        af[p + 3], f6[ci + 2], acc[ci], 0, 0, 0);
            }
            {
                const unsigned char* bp = lds + ubase + pbase[2];
#pragma unroll
                for (int ci = 0; ci < 4; ++ci) {
                    bf16x8 bfrag = *(const bf16x8*)(bp + ci * 544);
                    acc[ci] = __builtin_amdgcn_mfma_f32_32x32x16_bf16(
                        af[2], bfrag, acc[ci], 0, 0, 0);
                }
            }
#pragma unroll
            for (int p = 0; p < 5; ++p) af[p] = afn[p];
        }
    }

    float bv[16];
#pragma unroll
    for (int r = 0; r < 16; ++r) bv[r] = bias[(r & 3) + 8 * (r >> 2) + 4 * kh];

    const size_t sp_base = (((size_t)(a0 + ai) * 32 + (b0 + bi)) * 32 + c0);
#pragma unroll
    for (int ci = 0; ci < 4; ++ci) {
#pragma unroll
        for (int r = 0; r < 16; ++r) {
            int oc_ = (r & 3) + 8 * (r >> 2) + 4 * kh;
            out[(size_t)oc_ * X_IC_STRIDE + (sp_base + ci) * 32 + ln] = acc[ci][r] + bv[r];
        }
    }
}

extern "C" void kernel_launch(void* const* d_in, const int* in_sizes, int n_in,
                              void* d_out, int out_size, void* d_ws, size_t ws_size,
                              hipStream_t stream) {
    const float* x    = (const float*)d_in[0];
    const float* w    = (const float*)d_in[1];
    const float* bias = (const float*)d_in[2];
    float* out        = (float*)d_out;
    unsigned* wpack   = (unsigned*)d_ws;                       // 92160 B
    unsigned char* xpack = (unsigned char*)d_ws + XPACK_OFF;   // 32 MiB + 32 B

    if (ws_size >= (size_t)XPACK_OFF + XPACK_BYTES + 32) {
        pack_xw_kernel<<<dim3(2048), dim3(256), 0, stream>>>(x, w, xpack, wpack);
        conv4d_pipe<<<dim3(2048), dim3(256), 0, stream>>>(
            (const unsigned char*)d_ws, xpack, bias, out);
    } else {
        pack_w_kernel<<<dim3((WPACK_DWORDS + 255) / 256), dim3(256), 0, stream>>>(w, wpack);
        conv4d_legacy<<<dim3(2048), dim3(256), 0, stream>>>(
            x, (const unsigned char*)d_ws, bias, out);
    }
}